// Round 8
// baseline (1670.709 us; speedup 1.0000x reference)
//
#include <hip/hip_runtime.h>
#include <hip/hip_bf16.h>
#include <math.h>

#define NNODES 100000
#define EDIM 128
#define TSLOTS 750000
#define NB 391   // ceil(NNODES/256)
#define GRA 2344 // ceil(150000/64): blocks per relation in k_relf

typedef __bf16 bf16x8 __attribute__((ext_vector_type(8)));
typedef __bf16 bf16x4 __attribute__((ext_vector_type(4)));
typedef float f32x4 __attribute__((ext_vector_type(4)));

#define T_SCALE 17.312340490667562f    // 12*log2(e): t = (z+h)*T_SCALE
#define INV_SCALE 0.05776226504666211f // ln2/12
#define EMPTY_V (-3.0701134f)          // log(1e-16)/12

// mish(x) = x*tanh(softplus(x)) = x*(u^2+2u)/(u^2+2u+2), u=e^x
__device__ __forceinline__ float mishf(float x) {
  float u = __expf(fminf(x, 15.f));
  float num = u * (u + 2.f);
  return x * num * __builtin_amdgcn_rcpf(num + 2.f);
}

// 2^t as double (t pre-scaled by 12*log2e), fp32 exp2 + exponent bit-pack
__device__ __forceinline__ double exp12t(float t) {
  t = fmaxf(t, -20000.f);
  float ti = floorf(t);
  float m = exp2f(t - ti);
  int ei = (int)ti;
  ei = ei < -1000 ? -1000 : (ei > 1000 ? 1000 : ei);
  return (double)m * __longlong_as_double(((long long)(1023 + ei)) << 52);
}

// log(S)*ln2/12 via fp64 bit extraction; S<=0 (empty) -> log(1e-16)/12
__device__ __forceinline__ float logS12(double S) {
  if (!(S > 0.0)) return EMPTY_V;
  long long b = __double_as_longlong(S);
  int e2 = (int)((b >> 52) & 0x7FF) - 1023;
  float mf = __uint_as_float(0x3F800000u | (unsigned)((b >> 29) & 0x7FFFFF));
  return ((float)e2 + log2f(mf)) * INV_SCALE;
}

__global__ void k_sentinel(float* out, int n) {
  int i = blockIdx.x * 256 + threadIdx.x;
  if (i < n) out[i] = 1.0e6f;
}

// h0 (fp32) -> hb (bf16)
__global__ void k_init(const float* __restrict__ h0, __bf16* __restrict__ hb, int n8) {
  int i = blockIdx.x * 256 + threadIdx.x;
  if (i >= n8) return;
  float4 f0 = ((const float4*)h0)[i * 2];
  float4 f1 = ((const float4*)h0)[i * 2 + 1];
  bf16x8 p = {(__bf16)f0.x, (__bf16)f0.y, (__bf16)f0.z, (__bf16)f0.w,
              (__bf16)f1.x, (__bf16)f1.y, (__bf16)f1.z, (__bf16)f1.w};
  *(bf16x8*)(hb + (size_t)i * 8) = p;
}

struct TransDesc {
  const float* src[8];
  __bf16* dst[8];
  int R[8];
  int C[8];
  int tstart[9];
};

__global__ void k_transpose_all(TransDesc td) {
  __shared__ float tile[32][33];
  int b = blockIdx.x;
  int m = 0;
  while (m < 7 && b >= td.tstart[m + 1]) m++;
  int t = b - td.tstart[m];
  int R = td.R[m], C = td.C[m];
  int tcols = C >> 5;
  int by = t / tcols, bx = t - by * tcols;
  int tx = threadIdx.x & 31, ty = threadIdx.x >> 5;
  const float* src = td.src[m];
  __bf16* dst = td.dst[m];
  for (int i = 0; i < 32; i += 8)
    tile[ty + i][tx] = src[(size_t)(by * 32 + ty + i) * C + bx * 32 + tx];
  __syncthreads();
  for (int i = 0; i < 32; i += 8)
    dst[(size_t)(bx * 32 + ty + i) * R + by * 32 + tx] = (__bf16)tile[tx][ty + i];
}

// ================= CSR build =================
__device__ __forceinline__ int slot_node(int s, const int* at, const int* cl, const int* on) {
  if (s < 300000) return at[s];
  if (s < 450000) return cl[s - 300000];
  return on[s - 450000];
}

__global__ void k_count(const int* __restrict__ at, const int* __restrict__ cl,
                        const int* __restrict__ on, int* __restrict__ cnt) {
  int s = blockIdx.x * 256 + threadIdx.x;
  if (s >= TSLOTS) return;
  atomicAdd(&cnt[slot_node(s, at, cl, on)], 1);
}

__global__ void k_bsum(const int* __restrict__ cnt, int* __restrict__ bsum) {
  __shared__ int sm[256];
  int n = blockIdx.x * 256 + threadIdx.x;
  sm[threadIdx.x] = (n < NNODES) ? cnt[n] : 0;
  __syncthreads();
  for (int st = 128; st > 0; st >>= 1) {
    if (threadIdx.x < st) sm[threadIdx.x] += sm[threadIdx.x + st];
    __syncthreads();
  }
  if (threadIdx.x == 0) bsum[blockIdx.x] = sm[0];
}

__global__ void k_bscan(const int* __restrict__ bsum, int* __restrict__ bpre,
                        int* __restrict__ off) {
  __shared__ int sm[512];
  int t = threadIdx.x;
  int v = (t < NB) ? bsum[t] : 0;
  sm[t] = v;
  __syncthreads();
  for (int st = 1; st < 512; st <<= 1) {
    int x = (t >= st) ? sm[t - st] : 0;
    __syncthreads();
    sm[t] += x;
    __syncthreads();
  }
  if (t < NB) bpre[t] = sm[t] - v;
  if (t == NB - 1) off[NNODES] = sm[t];
}

__global__ void k_off(const int* __restrict__ cnt, const int* __restrict__ bpre,
                      int* __restrict__ off) {
  __shared__ int sm[256];
  int n = blockIdx.x * 256 + threadIdx.x;
  int v = (n < NNODES) ? cnt[n] : 0;
  sm[threadIdx.x] = v;
  __syncthreads();
  for (int st = 1; st < 256; st <<= 1) {
    int t = (threadIdx.x >= st) ? sm[threadIdx.x - st] : 0;
    __syncthreads();
    sm[threadIdx.x] += t;
    __syncthreads();
  }
  if (n < NNODES) off[n] = bpre[blockIdx.x] + sm[threadIdx.x] - v;
}

__global__ void k_fill(const int* __restrict__ at, const int* __restrict__ cl,
                       const int* __restrict__ on, const int* __restrict__ off,
                       int* __restrict__ cnt, int* __restrict__ perm) {
  int s = blockIdx.x * 256 + threadIdx.x;
  if (s >= TSLOTS) return;
  int node = slot_node(s, at, cl, on);
  int pos = atomicAdd(&cnt[node], -1) - 1;
  perm[s] = off[node] + pos;
}

// ================= fused relation kernel (round-5/6 verified form) =================
// 64 atoms/block, 512 threads / 8 waves. One dispatch for all three relations:
// blocks [0,GRA)=at, [GRA,2GRA)=on, [2GRA,3GRA)=cl.
// msg stores PRE-RESIDUAL z (fp16); residual h + T_SCALE applied in k_aggmlp.
struct RelAll {
  const int* av[3];
  const __bf16* wt1[3];
  const float* b1[3];
  const __bf16* wt2[3];
  const float* b2[3];
  const int* prm[3];
};

__global__ __launch_bounds__(512, 6) void k_relf(
    const float* __restrict__ hf, const __bf16* __restrict__ hb,
    RelAll ra, _Float16* __restrict__ msg) {
  __shared__ __align__(16) __bf16 xs[64][264];
  __shared__ int prm[128];
  const int tid = threadIdx.x;
  const int lane = tid & 63;
  const int w = tid >> 6;  // 0..7
  const int b = blockIdx.x;
  const int m = (b < GRA) ? 0 : (b < 2 * GRA ? 1 : 2);
  const int row0 = (b - m * GRA) * 64;
  const int A = 150000;
  const int* av = ra.av[m];
  const __bf16* wt1 = ra.wt1[m];
  const float* b1 = ra.b1[m];
  const __bf16* wt2 = ra.wt2[m];
  const float* b2 = ra.b2[m];
  const int* permrel = ra.prm[m];
  const int lhi = lane >> 4, llo = lane & 15;
  ushort* zs = (ushort*)&xs[0][0];  // fp16 view, row stride 264

  if (m < 2) {
    // ---------- arity-2 relation: K = N = 256 ----------
    if (tid < 128) {
      int i2 = row0 * 2 + tid;
      prm[tid] = (i2 < 2 * A) ? permrel[i2] : 0;
    }
    if (hb != nullptr) {
      for (int i = 0; i < 4; ++i) {
        int s = tid + i * 512;  // 2048 chunks: 64 rows x 32
        int r = s >> 5, o = s & 31;
        int a = row0 + r;
        uint4 v = {0, 0, 0, 0};
        if (a < A) {
          int node = av[2 * a + (o >> 4)];
          v = *(const uint4*)(hb + (size_t)node * 128 + (o & 15) * 8);
        }
        *(uint4*)&xs[r][o * 8] = v;
      }
    } else {
      for (int i = 0; i < 8; ++i) {
        int s = tid + i * 512;  // 4096: 64 rows x 64
        int r = s >> 6, o = s & 63;
        int a = row0 + r;
        float4 f = {0.f, 0.f, 0.f, 0.f};
        if (a < A) {
          int node = av[2 * a + (o >> 5)];
          f = *(const float4*)(hf + (size_t)node * 128 + (o & 31) * 4);
        }
        bf16x4 p = {(__bf16)f.x, (__bf16)f.y, (__bf16)f.z, (__bf16)f.w};
        *(bf16x4*)&xs[r][o * 4] = p;
      }
    }
    __syncthreads();

    const int cb = w * 32;  // 8 waves x 32 cols = 256
    f32x4 acc1[4][2];
#pragma unroll
    for (int rt = 0; rt < 4; rt++)
#pragma unroll
      for (int ct = 0; ct < 2; ct++) acc1[rt][ct] = (f32x4){0.f, 0.f, 0.f, 0.f};
#pragma unroll
    for (int kk = 0; kk < 8; ++kk) {
      int k = kk * 32 + lhi * 8;
      bf16x8 af[4], bfr[2];
#pragma unroll
      for (int rt = 0; rt < 4; rt++) af[rt] = *(const bf16x8*)&xs[rt * 16 + llo][k];
#pragma unroll
      for (int ct = 0; ct < 2; ct++)
        bfr[ct] = *(const bf16x8*)(wt1 + (size_t)(cb + ct * 16 + llo) * 256 + k);
#pragma unroll
      for (int rt = 0; rt < 4; rt++)
#pragma unroll
        for (int ct = 0; ct < 2; ct++)
          acc1[rt][ct] = __builtin_amdgcn_mfma_f32_16x16x32_bf16(af[rt], bfr[ct], acc1[rt][ct], 0, 0, 0);
    }
    __syncthreads();

    float b1v[2];
#pragma unroll
    for (int ct = 0; ct < 2; ct++) b1v[ct] = b1[cb + ct * 16 + llo];
#pragma unroll
    for (int rt = 0; rt < 4; rt++)
#pragma unroll
      for (int ct = 0; ct < 2; ct++)
#pragma unroll
        for (int i = 0; i < 4; i++)
          xs[rt * 16 + lhi * 4 + i][cb + ct * 16 + llo] = (__bf16)mishf(acc1[rt][ct][i] + b1v[ct]);
    __syncthreads();

    f32x4 acc2[4][2];
#pragma unroll
    for (int rt = 0; rt < 4; rt++)
#pragma unroll
      for (int ct = 0; ct < 2; ct++) acc2[rt][ct] = (f32x4){0.f, 0.f, 0.f, 0.f};
#pragma unroll
    for (int kk = 0; kk < 8; ++kk) {
      int k = kk * 32 + lhi * 8;
      bf16x8 af[4], bfr[2];
#pragma unroll
      for (int rt = 0; rt < 4; rt++) af[rt] = *(const bf16x8*)&xs[rt * 16 + llo][k];
#pragma unroll
      for (int ct = 0; ct < 2; ct++)
        bfr[ct] = *(const bf16x8*)(wt2 + (size_t)(cb + ct * 16 + llo) * 256 + k);
#pragma unroll
      for (int rt = 0; rt < 4; rt++)
#pragma unroll
        for (int ct = 0; ct < 2; ct++)
          acc2[rt][ct] = __builtin_amdgcn_mfma_f32_16x16x32_bf16(af[rt], bfr[ct], acc2[rt][ct], 0, 0, 0);
    }
    __syncthreads();

    float b2v[2];
#pragma unroll
    for (int ct = 0; ct < 2; ct++) b2v[ct] = b2[cb + ct * 16 + llo];
#pragma unroll
    for (int rt = 0; rt < 4; rt++)
#pragma unroll
      for (int ct = 0; ct < 2; ct++)
#pragma unroll
        for (int i = 0; i < 4; i++) {
          int r = rt * 16 + lhi * 4 + i;
          int col = cb + ct * 16 + llo;
          union { ushort u; _Float16 f; } cv;
          cv.f = (_Float16)(acc2[rt][ct][i] + b2v[ct]);
          zs[r * 264 + col] = cv.u;
        }
    __syncthreads();

    // pure LDS -> global coalesced scatter via perm
    for (int i = 0; i < 4; ++i) {
      int s = tid + i * 512;  // 2048: 128 slot-rows x 16 chunks
      int sr = s >> 4;
      int c = s & 15;
      int a = row0 + (sr >> 1);
      if (a < A) {
        int rr = sr >> 1, c0 = (sr & 1) * 128 + c * 8;
        uint4 z = *(const uint4*)&zs[rr * 264 + c0];
        *(uint4*)(msg + (size_t)prm[sr] * 128 + c * 8) = z;
      }
    }
  } else {
    // ---------- arity-1 relation: K = N = 128 ----------
    if (tid < 64) {
      int a = row0 + tid;
      prm[tid] = (a < A) ? permrel[a] : 0;
    }
    if (hb != nullptr) {
      for (int i = 0; i < 2; ++i) {
        int s = tid + i * 512;  // 1024: 64 rows x 16
        int r = s >> 4, o = s & 15;
        int a = row0 + r;
        uint4 v = {0, 0, 0, 0};
        if (a < A) {
          int node = av[a];
          v = *(const uint4*)(hb + (size_t)node * 128 + o * 8);
        }
        *(uint4*)&xs[r][o * 8] = v;
      }
    } else {
      for (int i = 0; i < 4; ++i) {
        int s = tid + i * 512;  // 2048: 64 rows x 32
        int r = s >> 5, o = s & 31;
        int a = row0 + r;
        float4 f = {0.f, 0.f, 0.f, 0.f};
        if (a < A) {
          int node = av[a];
          f = *(const float4*)(hf + (size_t)node * 128 + o * 4);
        }
        bf16x4 p = {(__bf16)f.x, (__bf16)f.y, (__bf16)f.z, (__bf16)f.w};
        *(bf16x4*)&xs[r][o * 4] = p;
      }
    }
    __syncthreads();

    const int cb = w * 16;  // 8 waves x 16 cols = 128
    f32x4 acc1[4];
#pragma unroll
    for (int rt = 0; rt < 4; rt++) acc1[rt] = (f32x4){0.f, 0.f, 0.f, 0.f};
#pragma unroll
    for (int kk = 0; kk < 4; ++kk) {
      int k = kk * 32 + lhi * 8;
      bf16x8 af[4], bfr;
#pragma unroll
      for (int rt = 0; rt < 4; rt++) af[rt] = *(const bf16x8*)&xs[rt * 16 + llo][k];
      bfr = *(const bf16x8*)(wt1 + (size_t)(cb + llo) * 128 + k);
#pragma unroll
      for (int rt = 0; rt < 4; rt++)
        acc1[rt] = __builtin_amdgcn_mfma_f32_16x16x32_bf16(af[rt], bfr, acc1[rt], 0, 0, 0);
    }
    __syncthreads();

    float b1v = b1[cb + llo];
#pragma unroll
    for (int rt = 0; rt < 4; rt++)
#pragma unroll
      for (int i = 0; i < 4; i++)
        xs[rt * 16 + lhi * 4 + i][cb + llo] = (__bf16)mishf(acc1[rt][i] + b1v);
    __syncthreads();

    f32x4 acc2[4];
#pragma unroll
    for (int rt = 0; rt < 4; rt++) acc2[rt] = (f32x4){0.f, 0.f, 0.f, 0.f};
#pragma unroll
    for (int kk = 0; kk < 4; ++kk) {
      int k = kk * 32 + lhi * 8;
      bf16x8 af[4], bfr;
#pragma unroll
      for (int rt = 0; rt < 4; rt++) af[rt] = *(const bf16x8*)&xs[rt * 16 + llo][k];
      bfr = *(const bf16x8*)(wt2 + (size_t)(cb + llo) * 128 + k);
#pragma unroll
      for (int rt = 0; rt < 4; rt++)
        acc2[rt] = __builtin_amdgcn_mfma_f32_16x16x32_bf16(af[rt], bfr, acc2[rt], 0, 0, 0);
    }
    __syncthreads();

    float b2v = b2[cb + llo];
#pragma unroll
    for (int rt = 0; rt < 4; rt++)
#pragma unroll
      for (int i = 0; i < 4; i++) {
        int r = rt * 16 + lhi * 4 + i;
        int col = cb + llo;
        union { ushort u; _Float16 f; } cv;
        cv.f = (_Float16)(acc2[rt][i] + b2v);
        zs[r * 264 + col] = cv.u;
      }
    __syncthreads();

    for (int i = 0; i < 2; ++i) {
      int s = tid + i * 512;  // 1024: 64 rows x 16
      int sr = s >> 4;
      int c = s & 15;
      int a = row0 + sr;
      if (a < A) {
        uint4 z = *(const uint4*)&zs[sr * 264 + c * 8];
        *(uint4*)(msg + (size_t)prm[sr] * 128 + c * 8) = z;
      }
    }
  }
}

// ======= FUSED aggregation + update MLP =======
// Phase A: 8 waves x 8 nodes = 64 nodes/block. Lane = (rg=lane>>4, fl=lane&15).
// d-loop now covers 8 ROWS per iteration via two independent uint4 loads per
// lane (rows d+rg and d+4+rg) issued back-to-back -- mean deg ~7.5 means most
// nodes finish in ONE exposed memory round instead of two. Next node's h row
// is prefetched before the shfl-reduce tail. Phase B: verified k_mlp body.
__global__ __launch_bounds__(512, 6) void k_aggmlp(
    const _Float16* __restrict__ msg, const int* __restrict__ off,
    const float* __restrict__ hin, const __bf16* __restrict__ hb,
    const __bf16* __restrict__ wt1, const float* __restrict__ b1,
    const __bf16* __restrict__ wt2, const float* __restrict__ b2,
    float* __restrict__ hout, __bf16* __restrict__ hbout) {
  __shared__ __align__(16) __bf16 xs[64][264];
  __shared__ int offs[65];
  const int tid = threadIdx.x;
  const int lane = tid & 63;
  const int w = tid >> 6;
  const int node0 = blockIdx.x * 64;
  const bool useb = (hbout != nullptr);

  if (tid < 65) {
    int n = node0 + tid;
    offs[tid] = off[n < NNODES ? n : NNODES];
  }
  // h staging (cols 128..255) -- issue before agg; hides under it
  if (useb) {
    for (int i = 0; i < 2; ++i) {
      int s = tid + i * 512;  // 1024: 64 rows x 16
      int r = s >> 4, o = s & 15;
      int n = node0 + r;
      uint4 v = {0, 0, 0, 0};
      if (n < NNODES) v = *(const uint4*)(hb + (size_t)n * 128 + o * 8);
      *(uint4*)&xs[r][128 + o * 8] = v;
    }
  } else {
    for (int i = 0; i < 4; ++i) {
      int s = tid + i * 512;  // 2048: 64 rows x 32
      int r = s >> 5, o = s & 31;
      int n = node0 + r;
      float4 f = {0.f, 0.f, 0.f, 0.f};
      if (n < NNODES) f = *(const float4*)(hin + (size_t)n * 128 + o * 4);
      bf16x4 p = {(__bf16)f.x, (__bf16)f.y, (__bf16)f.z, (__bf16)f.w};
      *(bf16x4*)&xs[r][128 + o * 4] = p;
    }
  }
  // zero agg cols for tail rows (only the last block)
  if (node0 + 64 > NNODES) {
    for (int s = tid; s < 64 * 16; s += 512) {
      int r = s >> 4, o = s & 15;
      if (node0 + r >= NNODES) *(uint4*)&xs[r][o * 8] = (uint4){0, 0, 0, 0};
    }
  }
  __syncthreads();  // offs visible (xs agg-cols written only after this)

  // ---- Phase A: aggregation ----
  const int rg = lane >> 4;   // row group 0..3
  const int fl = lane & 15;   // feature chunk: fl*8..+8
  const _Float16* mb = msg + fl * 8;

  // prefetch h for this wave's first node
  bf16x8 hq = {0, 0, 0, 0, 0, 0, 0, 0};
  float4 ha0 = {0.f, 0.f, 0.f, 0.f}, ha1 = {0.f, 0.f, 0.f, 0.f};
  {
    int nf = node0 + w * 8;
    if (nf < NNODES) {
      if (useb) hq = *(const bf16x8*)(hb + (size_t)nf * 128 + fl * 8);
      else {
        ha0 = *(const float4*)(hin + (size_t)nf * 128 + fl * 8);
        ha1 = *(const float4*)(hin + (size_t)nf * 128 + fl * 8 + 4);
      }
    }
  }

#pragma unroll 1
  for (int j = 0; j < 8; ++j) {
    int n = node0 + w * 8 + j;
    if (n >= NNODES) break;
    float h[8];
    if (useb) {
#pragma unroll
      for (int k = 0; k < 8; ++k) h[k] = (float)hq[k];
    } else {
      h[0] = ha0.x; h[1] = ha0.y; h[2] = ha0.z; h[3] = ha0.w;
      h[4] = ha1.x; h[5] = ha1.y; h[6] = ha1.z; h[7] = ha1.w;
    }
    int beg = offs[w * 8 + j];
    int deg = offs[w * 8 + j + 1] - beg;
    double S0 = 0.0, S1 = 0.0, S2 = 0.0, S3 = 0.0;
    double S4 = 0.0, S5 = 0.0, S6 = 0.0, S7 = 0.0;
#pragma unroll 1
    for (int d = 0; d < deg; d += 8) {
      int rp0 = d + rg;
      int rp1 = d + 4 + rg;
      int rc0 = rp0 < deg ? rp0 : deg - 1;
      int rc1 = rp1 < deg ? rp1 : deg - 1;
      // two INDEPENDENT loads in flight before either is consumed
      uint4 v0 = *(const uint4*)(mb + (size_t)(beg + rc0) * 128);
      uint4 v1 = *(const uint4*)(mb + (size_t)(beg + rc1) * 128);
      if (rp0 >= deg) { v0.x = 0xFC00FC00u; v0.y = 0xFC00FC00u; v0.z = 0xFC00FC00u; v0.w = 0xFC00FC00u; }
      if (rp1 >= deg) { v1.x = 0xFC00FC00u; v1.y = 0xFC00FC00u; v1.z = 0xFC00FC00u; v1.w = 0xFC00FC00u; }
      union { uint4 u; _Float16 f[8]; } q0, q1;
      q0.u = v0; q1.u = v1;
      S0 += exp12t(((float)q0.f[0] + h[0]) * T_SCALE) + exp12t(((float)q1.f[0] + h[0]) * T_SCALE);
      S1 += exp12t(((float)q0.f[1] + h[1]) * T_SCALE) + exp12t(((float)q1.f[1] + h[1]) * T_SCALE);
      S2 += exp12t(((float)q0.f[2] + h[2]) * T_SCALE) + exp12t(((float)q1.f[2] + h[2]) * T_SCALE);
      S3 += exp12t(((float)q0.f[3] + h[3]) * T_SCALE) + exp12t(((float)q1.f[3] + h[3]) * T_SCALE);
      S4 += exp12t(((float)q0.f[4] + h[4]) * T_SCALE) + exp12t(((float)q1.f[4] + h[4]) * T_SCALE);
      S5 += exp12t(((float)q0.f[5] + h[5]) * T_SCALE) + exp12t(((float)q1.f[5] + h[5]) * T_SCALE);
      S6 += exp12t(((float)q0.f[6] + h[6]) * T_SCALE) + exp12t(((float)q1.f[6] + h[6]) * T_SCALE);
      S7 += exp12t(((float)q0.f[7] + h[7]) * T_SCALE) + exp12t(((float)q1.f[7] + h[7]) * T_SCALE);
    }
    // prefetch next node's h before the shfl-reduce tail (hides under it)
    if (j < 7 && n + 1 < NNODES) {
      if (useb) hq = *(const bf16x8*)(hb + (size_t)(n + 1) * 128 + fl * 8);
      else {
        ha0 = *(const float4*)(hin + (size_t)(n + 1) * 128 + fl * 8);
        ha1 = *(const float4*)(hin + (size_t)(n + 1) * 128 + fl * 8 + 4);
      }
    }
    S0 += __shfl_xor(S0, 16); S0 += __shfl_xor(S0, 32);
    S1 += __shfl_xor(S1, 16); S1 += __shfl_xor(S1, 32);
    S2 += __shfl_xor(S2, 16); S2 += __shfl_xor(S2, 32);
    S3 += __shfl_xor(S3, 16); S3 += __shfl_xor(S3, 32);
    S4 += __shfl_xor(S4, 16); S4 += __shfl_xor(S4, 32);
    S5 += __shfl_xor(S5, 16); S5 += __shfl_xor(S5, 32);
    S6 += __shfl_xor(S6, 16); S6 += __shfl_xor(S6, 32);
    S7 += __shfl_xor(S7, 16); S7 += __shfl_xor(S7, 32);
    if (rg == 0) {
      bf16x8 r;
      r[0] = (__bf16)logS12(S0);
      r[1] = (__bf16)logS12(S1);
      r[2] = (__bf16)logS12(S2);
      r[3] = (__bf16)logS12(S3);
      r[4] = (__bf16)logS12(S4);
      r[5] = (__bf16)logS12(S5);
      r[6] = (__bf16)logS12(S6);
      r[7] = (__bf16)logS12(S7);
      *(bf16x8*)&xs[n - node0][fl * 8] = r;
    }
  }
  __syncthreads();

  // ---- Phase B: update MLP (verified k_mlp body) ----
  const int lhi = lane >> 4, llo = lane & 15;
  const int cb = w * 32;  // 8 waves x 32 cols = 256

  f32x4 acc1[4][2];
#pragma unroll
  for (int rt = 0; rt < 4; rt++)
#pragma unroll
    for (int ct = 0; ct < 2; ct++) acc1[rt][ct] = (f32x4){0.f, 0.f, 0.f, 0.f};
#pragma unroll
  for (int kk = 0; kk < 8; ++kk) {
    int k = kk * 32 + lhi * 8;
    bf16x8 af[4], bfr[2];
#pragma unroll
    for (int rt = 0; rt < 4; rt++) af[rt] = *(const bf16x8*)&xs[rt * 16 + llo][k];
#pragma unroll
    for (int ct = 0; ct < 2; ct++)
      bfr[ct] = *(const bf16x8*)(wt1 + (size_t)(cb + ct * 16 + llo) * 256 + k);
#pragma unroll
    for (int rt = 0; rt < 4; rt++)
#pragma unroll
      for (int ct = 0; ct < 2; ct++)
        acc1[rt][ct] = __builtin_amdgcn_mfma_f32_16x16x32_bf16(af[rt], bfr[ct], acc1[rt][ct], 0, 0, 0);
  }
  __syncthreads();

  float b1v[2];
#pragma unroll
  for (int ct = 0; ct < 2; ct++) b1v[ct] = b1[cb + ct * 16 + llo];
#pragma unroll
  for (int rt = 0; rt < 4; rt++)
#pragma unroll
    for (int ct = 0; ct < 2; ct++)
#pragma unroll
      for (int i = 0; i < 4; i++)
        xs[rt * 16 + lhi * 4 + i][cb + ct * 16 + llo] = (__bf16)mishf(acc1[rt][ct][i] + b1v[ct]);
  __syncthreads();

  const int cb2 = w * 16;  // 8 waves x 16 cols = 128
  f32x4 acc2[4];
#pragma unroll
  for (int rt = 0; rt < 4; rt++) acc2[rt] = (f32x4){0.f, 0.f, 0.f, 0.f};
#pragma unroll
  for (int kk = 0; kk < 8; ++kk) {
    int k = kk * 32 + lhi * 8;
    bf16x8 af[4], bfr;
#pragma unroll
    for (int rt = 0; rt < 4; rt++) af[rt] = *(const bf16x8*)&xs[rt * 16 + llo][k];
    bfr = *(const bf16x8*)(wt2 + (size_t)(cb2 + llo) * 256 + k);
#pragma unroll
    for (int rt = 0; rt < 4; rt++)
      acc2[rt] = __builtin_amdgcn_mfma_f32_16x16x32_bf16(af[rt], bfr, acc2[rt], 0, 0, 0);
  }

  float b2v = b2[cb2 + llo];
#pragma unroll
  for (int rt = 0; rt < 4; rt++)
#pragma unroll
    for (int i = 0; i < 4; i++) {
      int r = rt * 16 + lhi * 4 + i;
      int n = node0 + r;
      if (n >= NNODES) continue;
      int col = cb2 + llo;
      size_t idx = (size_t)n * 128 + col;
      float nh = hin[idx] + acc2[rt][i] + b2v;
      hout[idx] = nh;
      if (hbout != nullptr) hbout[idx] = (__bf16)nh;
    }
}

extern "C" void kernel_launch(void* const* d_in, const int* in_sizes, int n_in,
                              void* d_out, int out_size, void* d_ws, size_t ws_size,
                              hipStream_t stream) {
  const float* h0 = (const float*)d_in[0];
  const int* at = (const int*)d_in[1];
  const float* w_in_at = (const float*)d_in[2];
  const float* b_in_at = (const float*)d_in[3];
  const float* w_out_at = (const float*)d_in[4];
  const float* b_out_at = (const float*)d_in[5];
  const int* cl = (const int*)d_in[6];
  const float* w_in_cl = (const float*)d_in[7];
  const float* b_in_cl = (const float*)d_in[8];
  const float* w_out_cl = (const float*)d_in[9];
  const float* b_out_cl = (const float*)d_in[10];
  const int* on = (const int*)d_in[11];
  const float* w_in_on = (const float*)d_in[12];
  const float* b_in_on = (const float*)d_in[13];
  const float* w_out_on = (const float*)d_in[14];
  const float* b_out_on = (const float*)d_in[15];
  const float* w_u_in = (const float*)d_in[16];
  const float* b_u_in = (const float*)d_in[17];
  const float* w_u_out = (const float*)d_in[18];
  const float* b_u_out = (const float*)d_in[19];

  float* hout = (float*)d_out;
  char* ws = (char*)d_ws;

  const size_t MSG_B = (size_t)TSLOTS * 128 * 2;  // 192,000,000
  const size_t OFF_B = 400016;
  const size_t CNT_B = 400000;
  const size_t BS_B = 1568;
  const size_t PERM_B = 3000000;
  const size_t WT_B = 786432;
  const size_t MM_B = (size_t)NNODES * 128 * 2;   // 25,600,000 (unused now; layout kept)
  const size_t HB_B = (size_t)NNODES * 128 * 2;   // 25,600,000 (h bf16 shadow)
  const size_t REQ2 = MSG_B + OFF_B + CNT_B + 2 * BS_B + PERM_B + WT_B + MM_B;
  const size_t REQ3 = REQ2 + HB_B;

  if (ws_size < REQ2) {
    k_sentinel<<<(out_size + 255) / 256, 256, 0, stream>>>((float*)d_out, out_size);
    return;
  }

  _Float16* msg = (_Float16*)ws;
  int* off = (int*)(ws + MSG_B);
  int* cnt = (int*)(ws + MSG_B + OFF_B);
  int* bsum = (int*)(ws + MSG_B + OFF_B + CNT_B);
  int* bpre = (int*)(ws + MSG_B + OFF_B + CNT_B + BS_B);
  int* perm = (int*)(ws + MSG_B + OFF_B + CNT_B + 2 * BS_B);
  __bf16* wt = (__bf16*)(ws + MSG_B + OFF_B + CNT_B + 2 * BS_B + PERM_B);
  __bf16* hb = (ws_size >= REQ3) ? (__bf16*)(ws + REQ2) : nullptr;

  __bf16* wt_in_at = wt;
  __bf16* wt_out_at = wt + 65536;
  __bf16* wt_in_on = wt + 131072;
  __bf16* wt_out_on = wt + 196608;
  __bf16* wt_u_in = wt + 262144;
  __bf16* wt_u_out = wt + 327680;
  __bf16* wt_in_cl = wt + 360448;
  __bf16* wt_out_cl = wt + 376832;

  TransDesc td;
  const float* srcs[8] = {w_in_at, w_out_at, w_in_on, w_out_on, w_u_in, w_u_out, w_in_cl, w_out_cl};
  __bf16* dsts[8] = {wt_in_at, wt_out_at, wt_in_on, wt_out_on, wt_u_in, wt_u_out, wt_in_cl, wt_out_cl};
  int Rs[8] = {256, 256, 256, 256, 256, 256, 128, 128};
  int Cs[8] = {256, 256, 256, 256, 256, 128, 128, 128};
  int ts = 0;
  for (int m = 0; m < 8; ++m) {
    td.src[m] = srcs[m]; td.dst[m] = dsts[m]; td.R[m] = Rs[m]; td.C[m] = Cs[m];
    td.tstart[m] = ts; ts += (Rs[m] / 32) * (Cs[m] / 32);
  }
  td.tstart[8] = ts;
  k_transpose_all<<<384, 256, 0, stream>>>(td);

  if (hb) k_init<<<6250, 256, 0, stream>>>(h0, hb, NNODES * EDIM / 8);

  const int grid_mlp = (NNODES + 63) / 64;       // 1563
  const int grid_slots = (TSLOTS + 255) / 256;   // 2930

  hipMemsetAsync(cnt, 0, CNT_B, stream);
  k_count<<<grid_slots, 256, 0, stream>>>(at, cl, on, cnt);
  k_bsum<<<NB, 256, 0, stream>>>(cnt, bsum);
  k_bscan<<<1, 512, 0, stream>>>(bsum, bpre, off);
  k_off<<<NB, 256, 0, stream>>>(cnt, bpre, off);
  k_fill<<<grid_slots, 256, 0, stream>>>(at, cl, on, off, cnt, perm);

  RelAll ra;
  ra.av[0] = at;  ra.wt1[0] = wt_in_at; ra.b1[0] = b_in_at; ra.wt2[0] = wt_out_at; ra.b2[0] = b_out_at; ra.prm[0] = perm;
  ra.av[1] = on;  ra.wt1[1] = wt_in_on; ra.b1[1] = b_in_on; ra.wt2[1] = wt_out_on; ra.b2[1] = b_out_on; ra.prm[1] = perm + 450000;
  ra.av[2] = cl;  ra.wt1[2] = wt_in_cl; ra.b1[2] = b_in_cl; ra.wt2[2] = wt_out_cl; ra.b2[2] = b_out_cl; ra.prm[2] = perm + 300000;

  for (int l = 0; l < 4; ++l) {
    const float* hs = (l == 0) ? h0 : hout;
    k_relf<<<3 * GRA, 512, 0, stream>>>(hs, hb, ra, msg);
    k_aggmlp<<<grid_mlp, 512, 0, stream>>>(msg, off, hs, hb, wt_u_in, b_u_in, wt_u_out, b_u_out, hout, hb);
  }
}

// Round 9
// 1569.974 us; speedup vs baseline: 1.0642x; 1.0642x over previous
//
#include <hip/hip_runtime.h>
#include <hip/hip_bf16.h>
#include <math.h>

#define NNODES 100000
#define EDIM 128
#define TSLOTS 750000
#define NB 391   // ceil(NNODES/256)
#define GRA 2344 // ceil(150000/64): blocks per relation in k_relf

typedef __bf16 bf16x8 __attribute__((ext_vector_type(8)));
typedef __bf16 bf16x4 __attribute__((ext_vector_type(4)));
typedef float f32x4 __attribute__((ext_vector_type(4)));
typedef unsigned int u32x4 __attribute__((ext_vector_type(4)));

#define T_SCALE 17.312340490667562f    // 12*log2(e): t = (z+h)*T_SCALE
#define INV_SCALE 0.05776226504666211f // ln2/12
#define EMPTY_V (-3.0701134f)          // log(1e-16)/12

// mish(x) = x*tanh(softplus(x)) = x*(u^2+2u)/(u^2+2u+2), u=e^x
__device__ __forceinline__ float mishf(float x) {
  float u = __expf(fminf(x, 15.f));
  float num = u * (u + 2.f);
  return x * num * __builtin_amdgcn_rcpf(num + 2.f);
}

// 2^t as double (t pre-scaled by 12*log2e), fp32 exp2 + exponent bit-pack
__device__ __forceinline__ double exp12t(float t) {
  t = fmaxf(t, -20000.f);
  float ti = floorf(t);
  float m = exp2f(t - ti);
  int ei = (int)ti;
  ei = ei < -1000 ? -1000 : (ei > 1000 ? 1000 : ei);
  return (double)m * __longlong_as_double(((long long)(1023 + ei)) << 52);
}

// log(S)*ln2/12 via fp64 bit extraction; S<=0 (empty) -> log(1e-16)/12
__device__ __forceinline__ float logS12(double S) {
  if (!(S > 0.0)) return EMPTY_V;
  long long b = __double_as_longlong(S);
  int e2 = (int)((b >> 52) & 0x7FF) - 1023;
  float mf = __uint_as_float(0x3F800000u | (unsigned)((b >> 29) & 0x7FFFFF));
  return ((float)e2 + log2f(mf)) * INV_SCALE;
}

__global__ void k_sentinel(float* out, int n) {
  int i = blockIdx.x * 256 + threadIdx.x;
  if (i < n) out[i] = 1.0e6f;
}

// h0 (fp32) -> hb (bf16)
__global__ void k_init(const float* __restrict__ h0, __bf16* __restrict__ hb, int n8) {
  int i = blockIdx.x * 256 + threadIdx.x;
  if (i >= n8) return;
  float4 f0 = ((const float4*)h0)[i * 2];
  float4 f1 = ((const float4*)h0)[i * 2 + 1];
  bf16x8 p = {(__bf16)f0.x, (__bf16)f0.y, (__bf16)f0.z, (__bf16)f0.w,
              (__bf16)f1.x, (__bf16)f1.y, (__bf16)f1.z, (__bf16)f1.w};
  *(bf16x8*)(hb + (size_t)i * 8) = p;
}

struct TransDesc {
  const float* src[8];
  __bf16* dst[8];
  int R[8];
  int C[8];
  int tstart[9];
};

__global__ void k_transpose_all(TransDesc td) {
  __shared__ float tile[32][33];
  int b = blockIdx.x;
  int m = 0;
  while (m < 7 && b >= td.tstart[m + 1]) m++;
  int t = b - td.tstart[m];
  int R = td.R[m], C = td.C[m];
  int tcols = C >> 5;
  int by = t / tcols, bx = t - by * tcols;
  int tx = threadIdx.x & 31, ty = threadIdx.x >> 5;
  const float* src = td.src[m];
  __bf16* dst = td.dst[m];
  for (int i = 0; i < 32; i += 8)
    tile[ty + i][tx] = src[(size_t)(by * 32 + ty + i) * C + bx * 32 + tx];
  __syncthreads();
  for (int i = 0; i < 32; i += 8)
    dst[(size_t)(bx * 32 + ty + i) * R + by * 32 + tx] = (__bf16)tile[tx][ty + i];
}

// ================= CSR build =================
__device__ __forceinline__ int slot_node(int s, const int* at, const int* cl, const int* on) {
  if (s < 300000) return at[s];
  if (s < 450000) return cl[s - 300000];
  return on[s - 450000];
}

__global__ void k_count(const int* __restrict__ at, const int* __restrict__ cl,
                        const int* __restrict__ on, int* __restrict__ cnt) {
  int s = blockIdx.x * 256 + threadIdx.x;
  if (s >= TSLOTS) return;
  atomicAdd(&cnt[slot_node(s, at, cl, on)], 1);
}

__global__ void k_bsum(const int* __restrict__ cnt, int* __restrict__ bsum) {
  __shared__ int sm[256];
  int n = blockIdx.x * 256 + threadIdx.x;
  sm[threadIdx.x] = (n < NNODES) ? cnt[n] : 0;
  __syncthreads();
  for (int st = 128; st > 0; st >>= 1) {
    if (threadIdx.x < st) sm[threadIdx.x] += sm[threadIdx.x + st];
    __syncthreads();
  }
  if (threadIdx.x == 0) bsum[blockIdx.x] = sm[0];
}

__global__ void k_bscan(const int* __restrict__ bsum, int* __restrict__ bpre,
                        int* __restrict__ off) {
  __shared__ int sm[512];
  int t = threadIdx.x;
  int v = (t < NB) ? bsum[t] : 0;
  sm[t] = v;
  __syncthreads();
  for (int st = 1; st < 512; st <<= 1) {
    int x = (t >= st) ? sm[t - st] : 0;
    __syncthreads();
    sm[t] += x;
    __syncthreads();
  }
  if (t < NB) bpre[t] = sm[t] - v;
  if (t == NB - 1) off[NNODES] = sm[t];
}

__global__ void k_off(const int* __restrict__ cnt, const int* __restrict__ bpre,
                      int* __restrict__ off) {
  __shared__ int sm[256];
  int n = blockIdx.x * 256 + threadIdx.x;
  int v = (n < NNODES) ? cnt[n] : 0;
  sm[threadIdx.x] = v;
  __syncthreads();
  for (int st = 1; st < 256; st <<= 1) {
    int t = (threadIdx.x >= st) ? sm[threadIdx.x - st] : 0;
    __syncthreads();
    sm[threadIdx.x] += t;
    __syncthreads();
  }
  if (n < NNODES) off[n] = bpre[blockIdx.x] + sm[threadIdx.x] - v;
}

__global__ void k_fill(const int* __restrict__ at, const int* __restrict__ cl,
                       const int* __restrict__ on, const int* __restrict__ off,
                       int* __restrict__ cnt, int* __restrict__ perm) {
  int s = blockIdx.x * 256 + threadIdx.x;
  if (s >= TSLOTS) return;
  int node = slot_node(s, at, cl, on);
  int pos = atomicAdd(&cnt[node], -1) - 1;
  perm[s] = off[node] + pos;
}

// ================= fused relation kernel (round-5/6 verified form) =================
// 64 atoms/block, 512 threads / 8 waves. One dispatch for all three relations.
// msg stores PRE-RESIDUAL z (fp16) via NON-TEMPORAL stores: msg is a
// write-once/read-once 187.5 MB stream that otherwise washes hb (25.6 MB)
// out of L3 and turns the random gather into HBM misses (FETCH=134MB).
struct RelAll {
  const int* av[3];
  const __bf16* wt1[3];
  const float* b1[3];
  const __bf16* wt2[3];
  const float* b2[3];
  const int* prm[3];
};

__global__ __launch_bounds__(512, 6) void k_relf(
    const float* __restrict__ hf, const __bf16* __restrict__ hb,
    RelAll ra, _Float16* __restrict__ msg) {
  __shared__ __align__(16) __bf16 xs[64][264];
  __shared__ int prm[128];
  const int tid = threadIdx.x;
  const int lane = tid & 63;
  const int w = tid >> 6;  // 0..7
  const int b = blockIdx.x;
  const int m = (b < GRA) ? 0 : (b < 2 * GRA ? 1 : 2);
  const int row0 = (b - m * GRA) * 64;
  const int A = 150000;
  const int* av = ra.av[m];
  const __bf16* wt1 = ra.wt1[m];
  const float* b1 = ra.b1[m];
  const __bf16* wt2 = ra.wt2[m];
  const float* b2 = ra.b2[m];
  const int* permrel = ra.prm[m];
  const int lhi = lane >> 4, llo = lane & 15;
  ushort* zs = (ushort*)&xs[0][0];  // fp16 view, row stride 264

  if (m < 2) {
    // ---------- arity-2 relation: K = N = 256 ----------
    if (tid < 128) {
      int i2 = row0 * 2 + tid;
      prm[tid] = (i2 < 2 * A) ? permrel[i2] : 0;
    }
    if (hb != nullptr) {
      for (int i = 0; i < 4; ++i) {
        int s = tid + i * 512;  // 2048 chunks: 64 rows x 32
        int r = s >> 5, o = s & 31;
        int a = row0 + r;
        uint4 v = {0, 0, 0, 0};
        if (a < A) {
          int node = av[2 * a + (o >> 4)];
          v = *(const uint4*)(hb + (size_t)node * 128 + (o & 15) * 8);
        }
        *(uint4*)&xs[r][o * 8] = v;
      }
    } else {
      for (int i = 0; i < 8; ++i) {
        int s = tid + i * 512;  // 4096: 64 rows x 64
        int r = s >> 6, o = s & 63;
        int a = row0 + r;
        float4 f = {0.f, 0.f, 0.f, 0.f};
        if (a < A) {
          int node = av[2 * a + (o >> 5)];
          f = *(const float4*)(hf + (size_t)node * 128 + (o & 31) * 4);
        }
        bf16x4 p = {(__bf16)f.x, (__bf16)f.y, (__bf16)f.z, (__bf16)f.w};
        *(bf16x4*)&xs[r][o * 4] = p;
      }
    }
    __syncthreads();

    const int cb = w * 32;  // 8 waves x 32 cols = 256
    f32x4 acc1[4][2];
#pragma unroll
    for (int rt = 0; rt < 4; rt++)
#pragma unroll
      for (int ct = 0; ct < 2; ct++) acc1[rt][ct] = (f32x4){0.f, 0.f, 0.f, 0.f};
#pragma unroll
    for (int kk = 0; kk < 8; ++kk) {
      int k = kk * 32 + lhi * 8;
      bf16x8 af[4], bfr[2];
#pragma unroll
      for (int rt = 0; rt < 4; rt++) af[rt] = *(const bf16x8*)&xs[rt * 16 + llo][k];
#pragma unroll
      for (int ct = 0; ct < 2; ct++)
        bfr[ct] = *(const bf16x8*)(wt1 + (size_t)(cb + ct * 16 + llo) * 256 + k);
#pragma unroll
      for (int rt = 0; rt < 4; rt++)
#pragma unroll
        for (int ct = 0; ct < 2; ct++)
          acc1[rt][ct] = __builtin_amdgcn_mfma_f32_16x16x32_bf16(af[rt], bfr[ct], acc1[rt][ct], 0, 0, 0);
    }
    __syncthreads();

    float b1v[2];
#pragma unroll
    for (int ct = 0; ct < 2; ct++) b1v[ct] = b1[cb + ct * 16 + llo];
#pragma unroll
    for (int rt = 0; rt < 4; rt++)
#pragma unroll
      for (int ct = 0; ct < 2; ct++)
#pragma unroll
        for (int i = 0; i < 4; i++)
          xs[rt * 16 + lhi * 4 + i][cb + ct * 16 + llo] = (__bf16)mishf(acc1[rt][ct][i] + b1v[ct]);
    __syncthreads();

    f32x4 acc2[4][2];
#pragma unroll
    for (int rt = 0; rt < 4; rt++)
#pragma unroll
      for (int ct = 0; ct < 2; ct++) acc2[rt][ct] = (f32x4){0.f, 0.f, 0.f, 0.f};
#pragma unroll
    for (int kk = 0; kk < 8; ++kk) {
      int k = kk * 32 + lhi * 8;
      bf16x8 af[4], bfr[2];
#pragma unroll
      for (int rt = 0; rt < 4; rt++) af[rt] = *(const bf16x8*)&xs[rt * 16 + llo][k];
#pragma unroll
      for (int ct = 0; ct < 2; ct++)
        bfr[ct] = *(const bf16x8*)(wt2 + (size_t)(cb + ct * 16 + llo) * 256 + k);
#pragma unroll
      for (int rt = 0; rt < 4; rt++)
#pragma unroll
        for (int ct = 0; ct < 2; ct++)
          acc2[rt][ct] = __builtin_amdgcn_mfma_f32_16x16x32_bf16(af[rt], bfr[ct], acc2[rt][ct], 0, 0, 0);
    }
    __syncthreads();

    float b2v[2];
#pragma unroll
    for (int ct = 0; ct < 2; ct++) b2v[ct] = b2[cb + ct * 16 + llo];
#pragma unroll
    for (int rt = 0; rt < 4; rt++)
#pragma unroll
      for (int ct = 0; ct < 2; ct++)
#pragma unroll
        for (int i = 0; i < 4; i++) {
          int r = rt * 16 + lhi * 4 + i;
          int col = cb + ct * 16 + llo;
          union { ushort u; _Float16 f; } cv;
          cv.f = (_Float16)(acc2[rt][ct][i] + b2v[ct]);
          zs[r * 264 + col] = cv.u;
        }
    __syncthreads();

    // LDS -> global coalesced scatter via perm (non-temporal: stream past L3)
    for (int i = 0; i < 4; ++i) {
      int s = tid + i * 512;  // 2048: 128 slot-rows x 16 chunks
      int sr = s >> 4;
      int c = s & 15;
      int a = row0 + (sr >> 1);
      if (a < A) {
        int rr = sr >> 1, c0 = (sr & 1) * 128 + c * 8;
        u32x4 z = *(const u32x4*)&zs[rr * 264 + c0];
        __builtin_nontemporal_store(z, (u32x4*)(msg + (size_t)prm[sr] * 128 + c * 8));
      }
    }
  } else {
    // ---------- arity-1 relation: K = N = 128 ----------
    if (tid < 64) {
      int a = row0 + tid;
      prm[tid] = (a < A) ? permrel[a] : 0;
    }
    if (hb != nullptr) {
      for (int i = 0; i < 2; ++i) {
        int s = tid + i * 512;  // 1024: 64 rows x 16
        int r = s >> 4, o = s & 15;
        int a = row0 + r;
        uint4 v = {0, 0, 0, 0};
        if (a < A) {
          int node = av[a];
          v = *(const uint4*)(hb + (size_t)node * 128 + o * 8);
        }
        *(uint4*)&xs[r][o * 8] = v;
      }
    } else {
      for (int i = 0; i < 4; ++i) {
        int s = tid + i * 512;  // 2048: 64 rows x 32
        int r = s >> 5, o = s & 31;
        int a = row0 + r;
        float4 f = {0.f, 0.f, 0.f, 0.f};
        if (a < A) {
          int node = av[a];
          f = *(const float4*)(hf + (size_t)node * 128 + o * 4);
        }
        bf16x4 p = {(__bf16)f.x, (__bf16)f.y, (__bf16)f.z, (__bf16)f.w};
        *(bf16x4*)&xs[r][o * 4] = p;
      }
    }
    __syncthreads();

    const int cb = w * 16;  // 8 waves x 16 cols = 128
    f32x4 acc1[4];
#pragma unroll
    for (int rt = 0; rt < 4; rt++) acc1[rt] = (f32x4){0.f, 0.f, 0.f, 0.f};
#pragma unroll
    for (int kk = 0; kk < 4; ++kk) {
      int k = kk * 32 + lhi * 8;
      bf16x8 af[4], bfr;
#pragma unroll
      for (int rt = 0; rt < 4; rt++) af[rt] = *(const bf16x8*)&xs[rt * 16 + llo][k];
      bfr = *(const bf16x8*)(wt1 + (size_t)(cb + llo) * 128 + k);
#pragma unroll
      for (int rt = 0; rt < 4; rt++)
        acc1[rt] = __builtin_amdgcn_mfma_f32_16x16x32_bf16(af[rt], bfr, acc1[rt], 0, 0, 0);
    }
    __syncthreads();

    float b1v = b1[cb + llo];
#pragma unroll
    for (int rt = 0; rt < 4; rt++)
#pragma unroll
      for (int i = 0; i < 4; i++)
        xs[rt * 16 + lhi * 4 + i][cb + llo] = (__bf16)mishf(acc1[rt][i] + b1v);
    __syncthreads();

    f32x4 acc2[4];
#pragma unroll
    for (int rt = 0; rt < 4; rt++) acc2[rt] = (f32x4){0.f, 0.f, 0.f, 0.f};
#pragma unroll
    for (int kk = 0; kk < 4; ++kk) {
      int k = kk * 32 + lhi * 8;
      bf16x8 af[4], bfr;
#pragma unroll
      for (int rt = 0; rt < 4; rt++) af[rt] = *(const bf16x8*)&xs[rt * 16 + llo][k];
      bfr = *(const bf16x8*)(wt2 + (size_t)(cb + llo) * 128 + k);
#pragma unroll
      for (int rt = 0; rt < 4; rt++)
        acc2[rt] = __builtin_amdgcn_mfma_f32_16x16x32_bf16(af[rt], bfr, acc2[rt], 0, 0, 0);
    }
    __syncthreads();

    float b2v = b2[cb + llo];
#pragma unroll
    for (int rt = 0; rt < 4; rt++)
#pragma unroll
      for (int i = 0; i < 4; i++) {
        int r = rt * 16 + lhi * 4 + i;
        int col = cb + llo;
        union { ushort u; _Float16 f; } cv;
        cv.f = (_Float16)(acc2[rt][i] + b2v);
        zs[r * 264 + col] = cv.u;
      }
    __syncthreads();

    for (int i = 0; i < 2; ++i) {
      int s = tid + i * 512;  // 1024: 64 rows x 16
      int sr = s >> 4;
      int c = s & 15;
      int a = row0 + sr;
      if (a < A) {
        u32x4 z = *(const u32x4*)&zs[sr * 264 + c * 8];
        __builtin_nontemporal_store(z, (u32x4*)(msg + (size_t)prm[sr] * 128 + c * 8));
      }
    }
  }
}

// ======= FUSED aggregation + update MLP (round-6 verified form) =======
// Phase A: 8 waves x 8 nodes = 64 nodes/block; 4 rows in flight per wave;
// msg rows read NON-TEMPORALLY (read-once stream, keep hb in L3).
// Phase B: verified k_mlp body.
__global__ __launch_bounds__(512, 6) void k_aggmlp(
    const _Float16* __restrict__ msg, const int* __restrict__ off,
    const float* __restrict__ hin, const __bf16* __restrict__ hb,
    const __bf16* __restrict__ wt1, const float* __restrict__ b1,
    const __bf16* __restrict__ wt2, const float* __restrict__ b2,
    float* __restrict__ hout, __bf16* __restrict__ hbout) {
  __shared__ __align__(16) __bf16 xs[64][264];
  __shared__ int offs[65];
  const int tid = threadIdx.x;
  const int lane = tid & 63;
  const int w = tid >> 6;
  const int node0 = blockIdx.x * 64;
  const bool useb = (hbout != nullptr);

  if (tid < 65) {
    int n = node0 + tid;
    offs[tid] = off[n < NNODES ? n : NNODES];
  }
  // h staging (cols 128..255) -- issue before agg; hides under it
  if (useb) {
    for (int i = 0; i < 2; ++i) {
      int s = tid + i * 512;  // 1024: 64 rows x 16
      int r = s >> 4, o = s & 15;
      int n = node0 + r;
      uint4 v = {0, 0, 0, 0};
      if (n < NNODES) v = *(const uint4*)(hb + (size_t)n * 128 + o * 8);
      *(uint4*)&xs[r][128 + o * 8] = v;
    }
  } else {
    for (int i = 0; i < 4; ++i) {
      int s = tid + i * 512;  // 2048: 64 rows x 32
      int r = s >> 5, o = s & 31;
      int n = node0 + r;
      float4 f = {0.f, 0.f, 0.f, 0.f};
      if (n < NNODES) f = *(const float4*)(hin + (size_t)n * 128 + o * 4);
      bf16x4 p = {(__bf16)f.x, (__bf16)f.y, (__bf16)f.z, (__bf16)f.w};
      *(bf16x4*)&xs[r][128 + o * 4] = p;
    }
  }
  // zero agg cols for tail rows (only the last block)
  if (node0 + 64 > NNODES) {
    for (int s = tid; s < 64 * 16; s += 512) {
      int r = s >> 4, o = s & 15;
      if (node0 + r >= NNODES) *(uint4*)&xs[r][o * 8] = (uint4){0, 0, 0, 0};
    }
  }
  __syncthreads();  // offs visible (xs agg-cols written only after this)

  // ---- Phase A: aggregation ----
  const int rg = lane >> 4;   // row group 0..3
  const int fl = lane & 15;   // feature chunk: fl*8..+8
  const _Float16* mb = msg + fl * 8;

#pragma unroll 1
  for (int j = 0; j < 8; ++j) {
    int n = node0 + w * 8 + j;
    if (n >= NNODES) break;
    float h[8];
    if (useb) {
      bf16x8 hq = *(const bf16x8*)(hb + (size_t)n * 128 + fl * 8);
#pragma unroll
      for (int k = 0; k < 8; ++k) h[k] = (float)hq[k];
    } else {
      float4 a0 = *(const float4*)(hin + (size_t)n * 128 + fl * 8);
      float4 a1 = *(const float4*)(hin + (size_t)n * 128 + fl * 8 + 4);
      h[0] = a0.x; h[1] = a0.y; h[2] = a0.z; h[3] = a0.w;
      h[4] = a1.x; h[5] = a1.y; h[6] = a1.z; h[7] = a1.w;
    }
    int beg = offs[w * 8 + j];
    int deg = offs[w * 8 + j + 1] - beg;
    double S0 = 0.0, S1 = 0.0, S2 = 0.0, S3 = 0.0;
    double S4 = 0.0, S5 = 0.0, S6 = 0.0, S7 = 0.0;
#pragma unroll 1
    for (int d = 0; d < deg; d += 4) {
      int rp = d + rg;
      int rc = rp < deg ? rp : deg - 1;
      u32x4 v = __builtin_nontemporal_load((const u32x4*)(mb + (size_t)(beg + rc) * 128));
      if (rp >= deg) { v = (u32x4){0xFC00FC00u, 0xFC00FC00u, 0xFC00FC00u, 0xFC00FC00u}; }
      union { u32x4 u; _Float16 f[8]; } q;
      q.u = v;
      S0 += exp12t(((float)q.f[0] + h[0]) * T_SCALE);
      S1 += exp12t(((float)q.f[1] + h[1]) * T_SCALE);
      S2 += exp12t(((float)q.f[2] + h[2]) * T_SCALE);
      S3 += exp12t(((float)q.f[3] + h[3]) * T_SCALE);
      S4 += exp12t(((float)q.f[4] + h[4]) * T_SCALE);
      S5 += exp12t(((float)q.f[5] + h[5]) * T_SCALE);
      S6 += exp12t(((float)q.f[6] + h[6]) * T_SCALE);
      S7 += exp12t(((float)q.f[7] + h[7]) * T_SCALE);
    }
    S0 += __shfl_xor(S0, 16); S0 += __shfl_xor(S0, 32);
    S1 += __shfl_xor(S1, 16); S1 += __shfl_xor(S1, 32);
    S2 += __shfl_xor(S2, 16); S2 += __shfl_xor(S2, 32);
    S3 += __shfl_xor(S3, 16); S3 += __shfl_xor(S3, 32);
    S4 += __shfl_xor(S4, 16); S4 += __shfl_xor(S4, 32);
    S5 += __shfl_xor(S5, 16); S5 += __shfl_xor(S5, 32);
    S6 += __shfl_xor(S6, 16); S6 += __shfl_xor(S6, 32);
    S7 += __shfl_xor(S7, 16); S7 += __shfl_xor(S7, 32);
    if (rg == 0) {
      bf16x8 r;
      r[0] = (__bf16)logS12(S0);
      r[1] = (__bf16)logS12(S1);
      r[2] = (__bf16)logS12(S2);
      r[3] = (__bf16)logS12(S3);
      r[4] = (__bf16)logS12(S4);
      r[5] = (__bf16)logS12(S5);
      r[6] = (__bf16)logS12(S6);
      r[7] = (__bf16)logS12(S7);
      *(bf16x8*)&xs[n - node0][fl * 8] = r;
    }
  }
  __syncthreads();

  // ---- Phase B: update MLP (verified k_mlp body) ----
  const int lhi = lane >> 4, llo = lane & 15;
  const int cb = w * 32;  // 8 waves x 32 cols = 256

  f32x4 acc1[4][2];
#pragma unroll
  for (int rt = 0; rt < 4; rt++)
#pragma unroll
    for (int ct = 0; ct < 2; ct++) acc1[rt][ct] = (f32x4){0.f, 0.f, 0.f, 0.f};
#pragma unroll
  for (int kk = 0; kk < 8; ++kk) {
    int k = kk * 32 + lhi * 8;
    bf16x8 af[4], bfr[2];
#pragma unroll
    for (int rt = 0; rt < 4; rt++) af[rt] = *(const bf16x8*)&xs[rt * 16 + llo][k];
#pragma unroll
    for (int ct = 0; ct < 2; ct++)
      bfr[ct] = *(const bf16x8*)(wt1 + (size_t)(cb + ct * 16 + llo) * 256 + k);
#pragma unroll
    for (int rt = 0; rt < 4; rt++)
#pragma unroll
      for (int ct = 0; ct < 2; ct++)
        acc1[rt][ct] = __builtin_amdgcn_mfma_f32_16x16x32_bf16(af[rt], bfr[ct], acc1[rt][ct], 0, 0, 0);
  }
  __syncthreads();

  float b1v[2];
#pragma unroll
  for (int ct = 0; ct < 2; ct++) b1v[ct] = b1[cb + ct * 16 + llo];
#pragma unroll
  for (int rt = 0; rt < 4; rt++)
#pragma unroll
    for (int ct = 0; ct < 2; ct++)
#pragma unroll
      for (int i = 0; i < 4; i++)
        xs[rt * 16 + lhi * 4 + i][cb + ct * 16 + llo] = (__bf16)mishf(acc1[rt][ct][i] + b1v[ct]);
  __syncthreads();

  const int cb2 = w * 16;  // 8 waves x 16 cols = 128
  f32x4 acc2[4];
#pragma unroll
  for (int rt = 0; rt < 4; rt++) acc2[rt] = (f32x4){0.f, 0.f, 0.f, 0.f};
#pragma unroll
  for (int kk = 0; kk < 8; ++kk) {
    int k = kk * 32 + lhi * 8;
    bf16x8 af[4], bfr;
#pragma unroll
    for (int rt = 0; rt < 4; rt++) af[rt] = *(const bf16x8*)&xs[rt * 16 + llo][k];
    bfr = *(const bf16x8*)(wt2 + (size_t)(cb2 + llo) * 256 + k);
#pragma unroll
    for (int rt = 0; rt < 4; rt++)
      acc2[rt] = __builtin_amdgcn_mfma_f32_16x16x32_bf16(af[rt], bfr, acc2[rt], 0, 0, 0);
  }

  float b2v = b2[cb2 + llo];
#pragma unroll
  for (int rt = 0; rt < 4; rt++)
#pragma unroll
    for (int i = 0; i < 4; i++) {
      int r = rt * 16 + lhi * 4 + i;
      int n = node0 + r;
      if (n >= NNODES) continue;
      int col = cb2 + llo;
      size_t idx = (size_t)n * 128 + col;
      float nh = hin[idx] + acc2[rt][i] + b2v;
      hout[idx] = nh;
      if (hbout != nullptr) hbout[idx] = (__bf16)nh;
    }
}

extern "C" void kernel_launch(void* const* d_in, const int* in_sizes, int n_in,
                              void* d_out, int out_size, void* d_ws, size_t ws_size,
                              hipStream_t stream) {
  const float* h0 = (const float*)d_in[0];
  const int* at = (const int*)d_in[1];
  const float* w_in_at = (const float*)d_in[2];
  const float* b_in_at = (const float*)d_in[3];
  const float* w_out_at = (const float*)d_in[4];
  const float* b_out_at = (const float*)d_in[5];
  const int* cl = (const int*)d_in[6];
  const float* w_in_cl = (const float*)d_in[7];
  const float* b_in_cl = (const float*)d_in[8];
  const float* w_out_cl = (const float*)d_in[9];
  const float* b_out_cl = (const float*)d_in[10];
  const int* on = (const int*)d_in[11];
  const float* w_in_on = (const float*)d_in[12];
  const float* b_in_on = (const float*)d_in[13];
  const float* w_out_on = (const float*)d_in[14];
  const float* b_out_on = (const float*)d_in[15];
  const float* w_u_in = (const float*)d_in[16];
  const float* b_u_in = (const float*)d_in[17];
  const float* w_u_out = (const float*)d_in[18];
  const float* b_u_out = (const float*)d_in[19];

  float* hout = (float*)d_out;
  char* ws = (char*)d_ws;

  const size_t MSG_B = (size_t)TSLOTS * 128 * 2;  // 192,000,000
  const size_t OFF_B = 400016;
  const size_t CNT_B = 400000;
  const size_t BS_B = 1568;
  const size_t PERM_B = 3000000;
  const size_t WT_B = 786432;
  const size_t MM_B = (size_t)NNODES * 128 * 2;   // 25,600,000 (unused now; layout kept)
  const size_t HB_B = (size_t)NNODES * 128 * 2;   // 25,600,000 (h bf16 shadow)
  const size_t REQ2 = MSG_B + OFF_B + CNT_B + 2 * BS_B + PERM_B + WT_B + MM_B;
  const size_t REQ3 = REQ2 + HB_B;

  if (ws_size < REQ2) {
    k_sentinel<<<(out_size + 255) / 256, 256, 0, stream>>>((float*)d_out, out_size);
    return;
  }

  _Float16* msg = (_Float16*)ws;
  int* off = (int*)(ws + MSG_B);
  int* cnt = (int*)(ws + MSG_B + OFF_B);
  int* bsum = (int*)(ws + MSG_B + OFF_B + CNT_B);
  int* bpre = (int*)(ws + MSG_B + OFF_B + CNT_B + BS_B);
  int* perm = (int*)(ws + MSG_B + OFF_B + CNT_B + 2 * BS_B);
  __bf16* wt = (__bf16*)(ws + MSG_B + OFF_B + CNT_B + 2 * BS_B + PERM_B);
  __bf16* hb = (ws_size >= REQ3) ? (__bf16*)(ws + REQ2) : nullptr;

  __bf16* wt_in_at = wt;
  __bf16* wt_out_at = wt + 65536;
  __bf16* wt_in_on = wt + 131072;
  __bf16* wt_out_on = wt + 196608;
  __bf16* wt_u_in = wt + 262144;
  __bf16* wt_u_out = wt + 327680;
  __bf16* wt_in_cl = wt + 360448;
  __bf16* wt_out_cl = wt + 376832;

  TransDesc td;
  const float* srcs[8] = {w_in_at, w_out_at, w_in_on, w_out_on, w_u_in, w_u_out, w_in_cl, w_out_cl};
  __bf16* dsts[8] = {wt_in_at, wt_out_at, wt_in_on, wt_out_on, wt_u_in, wt_u_out, wt_in_cl, wt_out_cl};
  int Rs[8] = {256, 256, 256, 256, 256, 256, 128, 128};
  int Cs[8] = {256, 256, 256, 256, 256, 128, 128, 128};
  int ts = 0;
  for (int m = 0; m < 8; ++m) {
    td.src[m] = srcs[m]; td.dst[m] = dsts[m]; td.R[m] = Rs[m]; td.C[m] = Cs[m];
    td.tstart[m] = ts; ts += (Rs[m] / 32) * (Cs[m] / 32);
  }
  td.tstart[8] = ts;
  k_transpose_all<<<384, 256, 0, stream>>>(td);

  if (hb) k_init<<<6250, 256, 0, stream>>>(h0, hb, NNODES * EDIM / 8);

  const int grid_mlp = (NNODES + 63) / 64;       // 1563
  const int grid_slots = (TSLOTS + 255) / 256;   // 2930

  hipMemsetAsync(cnt, 0, CNT_B, stream);
  k_count<<<grid_slots, 256, 0, stream>>>(at, cl, on, cnt);
  k_bsum<<<NB, 256, 0, stream>>>(cnt, bsum);
  k_bscan<<<1, 512, 0, stream>>>(bsum, bpre, off);
  k_off<<<NB, 256, 0, stream>>>(cnt, bpre, off);
  k_fill<<<grid_slots, 256, 0, stream>>>(at, cl, on, off, cnt, perm);

  RelAll ra;
  ra.av[0] = at;  ra.wt1[0] = wt_in_at; ra.b1[0] = b_in_at; ra.wt2[0] = wt_out_at; ra.b2[0] = b_out_at; ra.prm[0] = perm;
  ra.av[1] = on;  ra.wt1[1] = wt_in_on; ra.b1[1] = b_in_on; ra.wt2[1] = wt_out_on; ra.b2[1] = b_out_on; ra.prm[1] = perm + 450000;
  ra.av[2] = cl;  ra.wt1[2] = wt_in_cl; ra.b1[2] = b_in_cl; ra.wt2[2] = wt_out_cl; ra.b2[2] = b_out_cl; ra.prm[2] = perm + 300000;

  for (int l = 0; l < 4; ++l) {
    const float* hs = (l == 0) ? h0 : hout;
    k_relf<<<3 * GRA, 512, 0, stream>>>(hs, hb, ra, msg);
    k_aggmlp<<<grid_mlp, 512, 0, stream>>>(msg, off, hs, hb, wt_u_in, b_u_in, wt_u_out, b_u_out, hout, hb);
  }
}